// Round 14
// baseline (318.607 us; speedup 1.0000x reference)
//
#include <hip/hip_runtime.h>
#include <hip/hip_bf16.h>
#include <math.h>

#define DD 128
#define DH 64
#define MAXN_F (1.0f - 4e-3f)
#define NB_GEMM 1280

__device__ inline float wsum(float v) {
#pragma unroll
    for (int off = 32; off > 0; off >>= 1) v += __shfl_xor(v, off, 64);
    return v;
}
__device__ inline float wsum32(float v) {
#pragma unroll
    for (int off = 16; off > 0; off >>= 1) v += __shfl_xor(v, off, 32);
    return v;
}
__device__ inline float wmax(float v) {
#pragma unroll
    for (int off = 32; off > 0; off >>= 1) v = fmaxf(v, __shfl_xor(v, off, 64));
    return v;
}
__device__ inline int wsumi(int v) {
#pragma unroll
    for (int off = 32; off > 0; off >>= 1) v += __shfl_xor(v, off, 64);
    return v;
}
__device__ inline unsigned short f2bf16(float x) {
    unsigned u = __float_as_uint(x);
    u += 0x7fffu + ((u >> 16) & 1u);   // RNE
    return (unsigned short)(u >> 16);
}
__device__ inline float bf162f(unsigned short h) {
    return __uint_as_float(((unsigned)h) << 16);
}
__device__ inline unsigned packbf(float a, float b) {
    return (unsigned)f2bf16(a) | ((unsigned)f2bf16(b) << 16);
}
// fast hyperbolics on HW exp2/log2 (args >= 0 here)
__device__ inline float fatanh(float z) {
    return 0.5f * __logf(__fdividef(1.f + z, 1.f - z));
}
__device__ inline float ftanh(float y) {
    y = fminf(y, 10.f);                  // tanh(10)=1-4e-9; avoids inf/inf
    float e = __expf(2.f * y);
    return __fdividef(e - 1.f, e + 1.f);
}

// ---- W-in-LDS wave-per-row fused kernel --------------------------------
// Stage W once (fp32->bf16, XOR-swizzled, 32 KB). Each wave grid-strides
// rows; lane l owns cols l (head0) and 64+l (head1): 2 accumulators, all
// reductions are 64-lane wsums, no block barriers in the row loop.
__global__ __launch_bounds__(256) void gemm_node_k(
    const float* __restrict__ x, const float* __restrict__ W,
    const float* __restrict__ bias,
    const float* __restrict__ atti, const float* __restrict__ attj,
    const int* __restrict__ eidx, int* __restrict__ deg,
    unsigned* __restrict__ xtb, float* __restrict__ ai, float* __restrict__ aj,
    int n, int E) {
    __shared__ ushort4 wlds[128 * 32];   // 32 KB bf16 W, swizzled
    const int tid = threadIdx.x;
    const int lane = tid & 63;
    const int l31 = lane & 31;
    const float4* x4 = reinterpret_cast<const float4*>(x);
    const float4* W4 = reinterpret_cast<const float4*>(W);
    // ---- stage W ----
#pragma unroll
    for (int i = 0; i < 16; ++i) {
        int s = tid + i * 256;           // 0..4095
        int c = s >> 5, kk = s & 31;
        float4 v = W4[c * 32 + kk];
        ushort4 h;
        h.x = f2bf16(v.x); h.y = f2bf16(v.y); h.z = f2bf16(v.z); h.w = f2bf16(v.w);
        wlds[c * 32 + (kk ^ (c & 31))] = h;
    }
    // ---- per-wave bias/att pipeline (registers only) ----
    float b0 = bias[lane], b1 = bias[64 + lane];
    float ai0 = atti[lane], ai1 = atti[64 + lane];
    float aj0 = attj[lane], aj1 = attj[64 + lane];
    float Sb = wsum(b0 * b0 + b1 * b1);
    float nb_ = fmaxf(sqrtf(Sb), 1e-15f);
    float th = tanhf(nb_) / nb_;
    float e0 = th * b0, e1 = th * b1;
    float Se = wsum(e0 * e0 + e1 * e1);
    float ne = fmaxf(sqrtf(Se), 1e-15f);
    if (ne > MAXN_F) { float sc = MAXN_F / ne; e0 *= sc; e1 *= sc; }
    float y2v = wsum(e0 * e0 + e1 * e1);
    float Yi0 = wsum(e0 * ai0), Yi1 = wsum(e1 * ai1);
    float Yj0 = wsum(e0 * aj0), Yj1 = wsum(e1 * aj1);
    __syncthreads();  // W staged
    // ---- row loop: one wave per row, grid-stride ----
    const int gw = blockIdx.x * 4 + (tid >> 6);
    const int nw = gridDim.x * 4;
    const ushort4* w0p = wlds + lane * 32;
    const ushort4* w1p = wlds + (lane + 64) * 32;
    for (int r = gw; r < n; r += nw) {
        const size_t rb = (size_t)r * 32;
        float4 xv = x4[rb + l31];
        float Sx = wsum32(xv.x * xv.x + xv.y * xv.y + xv.z * xv.z + xv.w * xv.w);
        float m0 = 0.f, m1 = 0.f;
#pragma unroll 4
        for (int k4 = 0; k4 < 32; ++k4) {
            float4 xb = x4[rb + k4];     // uniform address: HW broadcast
            int p = k4 ^ l31;
            ushort4 w0 = w0p[p];
            ushort4 w1 = w1p[p];
            m0 += xb.x * bf162f(w0.x) + xb.y * bf162f(w0.y) +
                  xb.z * bf162f(w0.z) + xb.w * bf162f(w0.w);
            m1 += xb.x * bf162f(w1.x) + xb.y * bf162f(w1.y) +
                  xb.z * bf162f(w1.z) + xb.w * bf162f(w1.w);
        }
        // 6 per-row scalars via 64-lane reductions
        float Sm  = wsum(m0 * m0 + m1 * m1);
        float My  = wsum(m0 * e0 + m1 * e1);
        float Di0 = wsum(m0 * ai0), Di1 = wsum(m1 * ai1);
        float Dj0 = wsum(m0 * aj0), Dj1 = wsum(m1 * aj1);
        // analytic scalar chain (redundant on all lanes)
        float xn = fmaxf(sqrtf(Sx), 1e-15f);
        float mxn = fmaxf(sqrtf(Sm), 1e-15f);
        float art = fatanh(fminf(xn, 1.f - 1e-7f));
        float tn = ftanh(__fdividef(mxn, xn) * art);
        float rho = (Sm == 0.f) ? 0.f : __fdividef(tn, mxn);
        float pn = (Sm == 0.f) ? 0.f : tn;
        if (pn > MAXN_F) { rho *= MAXN_F / pn; pn = MAXN_F; }
        float X2 = pn * pn, XY = rho * My;
        float ca = 1.f + 2.f * XY + y2v;
        float cb = 1.f - X2;
        float dn = fmaxf(1.f + 2.f * XY + X2 * y2v, 1e-15f);
        float Sh = __fdividef(ca * ca * X2 + 2.f * ca * cb * XY + cb * cb * y2v,
                              dn * dn);
        float nraw = fmaxf(sqrtf(Sh), 1e-15f);
        float scp = 1.f, nh = nraw;
        if (nraw > MAXN_F) { scp = MAXN_F / nraw; nh = MAXN_F; }
        float g = __fdividef(fatanh(fminf(nh, 1.f - 1e-7f)), nh);
        float gs = __fdividef(g * scp, dn);
        float al = gs * ca * rho;
        float be = gs * cb;
        xtb[(size_t)r * DH + lane] = packbf(al * m0 + be * e0, al * m1 + be * e1);
        if (lane == 0) {
            reinterpret_cast<float2*>(ai)[r] =
                make_float2(al * Di0 + be * Yi0, al * Di1 + be * Yi1);
            reinterpret_cast<float2*>(aj)[r] =
                make_float2(al * Dj0 + be * Yj0, al * Dj1 + be * Yj1);
        }
    }
    // ---- edge histogram tail ----
    {
        int perB = (E + gridDim.x - 1) / gridDim.x;
        int eb = blockIdx.x * perB;
        int ee = min(E, eb + perB);
        for (int e = eb + tid; e < ee; e += 256) atomicAdd(&deg[eidx[e]], 1);
    }
}

// ---------------- scan1: per-1024-chunk sums ----------------
__global__ __launch_bounds__(256) void scan1_k(const int* __restrict__ deg,
                                               int* __restrict__ bsum, int n) {
    int b = blockIdx.x, tid = threadIdx.x;
    int i0 = b * 1024 + tid * 4;
    int s = 0;
#pragma unroll
    for (int k = 0; k < 4; ++k)
        if (i0 + k < n) s += deg[i0 + k];
    s = wsumi(s);
    __shared__ int sm[4];
    if ((tid & 63) == 0) sm[tid >> 6] = s;
    __syncthreads();
    if (tid == 0) bsum[b] = sm[0] + sm[1] + sm[2] + sm[3];
}

// ---------------- scan23: top-level scan + rowptr/cursor ----------------
__global__ __launch_bounds__(256) void scan23_k(const int* __restrict__ deg,
                                                const int* __restrict__ bsum,
                                                int* __restrict__ rowptr,
                                                int* __restrict__ cursor,
                                                int n, int E, int nb) {
    int b = blockIdx.x, tid = threadIdx.x;
    __shared__ int sm2[256];
    int v = (tid < nb) ? bsum[tid] : 0;
    sm2[tid] = v;
    __syncthreads();
    for (int off = 1; off < 256; off <<= 1) {
        int u = (tid >= off) ? sm2[tid - off] : 0;
        __syncthreads();
        sm2[tid] += u;
        __syncthreads();
    }
    __shared__ int myoff;
    if (tid == 0) myoff = sm2[b] - bsum[b];
    __syncthreads();
    int i0 = b * 1024 + tid * 4;
    int d[4];
#pragma unroll
    for (int k = 0; k < 4; ++k) d[k] = (i0 + k < n) ? deg[i0 + k] : 0;
    int ts = d[0] + d[1] + d[2] + d[3];
    __shared__ int sm[256];
    sm[tid] = ts;
    __syncthreads();
    for (int off = 1; off < 256; off <<= 1) {
        int u = (tid >= off) ? sm[tid - off] : 0;
        __syncthreads();
        sm[tid] += u;
        __syncthreads();
    }
    int base = myoff + sm[tid] - ts;
    int pre = 0;
#pragma unroll
    for (int k = 0; k < 4; ++k) {
        if (i0 + k < n) {
            rowptr[i0 + k] = base + pre;
            cursor[i0 + k] = base + pre;
        }
        pre += d[k];
    }
    if (b == 0 && tid == 0) rowptr[n] = E;
}

// ---------------- CSR scatter ----------------
__global__ __launch_bounds__(256) void scatter_k(const int* __restrict__ eidx,
                                                 int* __restrict__ cursor,
                                                 int* __restrict__ csrc, int E) {
    int e = blockIdx.x * 256 + threadIdx.x;
    if (e >= E) return;
    int t = eidx[e], s = eidx[E + e];
    int pos = atomicAdd(&cursor[t], 1);
    csrc[pos] = s;
}

// ---------------- fused softmax + aggregation + HypAct ----------------
__global__ __launch_bounds__(256) void agg_fused_k(
    const int* __restrict__ rowptr, const int* __restrict__ csrc,
    const float* __restrict__ ai, const float* __restrict__ aj,
    const unsigned* __restrict__ xtb, float* __restrict__ out, int n) {
    int t = (blockIdx.x * 256 + threadIdx.x) >> 6;
    int lane = threadIdx.x & 63;
    if (t >= n) return;
    const int beg = rowptr[t];
    const int deg = rowptr[t + 1] - beg;
    const int cnt = deg + 1;  // + self loop
    float2 ait = reinterpret_cast<const float2*>(ai)[t];
    const float2* aj2 = reinterpret_cast<const float2*>(aj);
    float u;
    if (cnt <= 64) {
        // ---- single-pass fast path ----
        int s_ = t;
        if (lane < deg) s_ = csrc[beg + lane];
        float a0 = -1e30f, a1 = -1e30f;
        if (lane < cnt) {
            float2 av = aj2[s_];
            a0 = ait.x + av.x; a0 = a0 < 0.f ? 0.2f * a0 : a0;
            a1 = ait.y + av.y; a1 = a1 < 0.f ? 0.2f * a1 : a1;
        }
        float mx0 = wmax(a0), mx1 = wmax(a1);
        float e0 = (lane < cnt) ? expf(a0 - mx0) : 0.f;
        float e1 = (lane < cnt) ? expf(a1 - mx1) : 0.f;
        float den0 = wsum(e0), den1 = wsum(e1);
        float w0s = 0.5f * e0 / (den0 + 1e-16f);
        float w1s = 0.5f * e1 / (den1 + 1e-16f);
        float acc = 0.f;
        for (int j = 0; j < cnt; ++j) {
            int sj = __shfl(s_, j, 64);
            float w0 = __shfl(w0s, j, 64);
            float w1 = __shfl(w1s, j, 64);
            unsigned v = xtb[(size_t)sj * DH + lane];
            acc += w0 * __uint_as_float(v << 16) +
                   w1 * __uint_as_float(v & 0xffff0000u);
        }
        u = acc;
    } else {
        // ---- general two-pass path (rare: deg > 63) ----
        float mx0 = -1e30f, mx1 = -1e30f;
        for (int bs = 0; bs < cnt; bs += 64) {
            int idx = bs + lane;
            float a0 = -1e30f, a1 = -1e30f;
            if (idx < cnt) {
                int s = (idx < deg) ? csrc[beg + idx] : t;
                float2 av = aj2[s];
                a0 = ait.x + av.x; a0 = a0 < 0.f ? 0.2f * a0 : a0;
                a1 = ait.y + av.y; a1 = a1 < 0.f ? 0.2f * a1 : a1;
            }
            mx0 = fmaxf(mx0, a0);
            mx1 = fmaxf(mx1, a1);
        }
        mx0 = wmax(mx0);
        mx1 = wmax(mx1);
        float acc0 = 0.f, acc1 = 0.f, den0 = 0.f, den1 = 0.f;
        for (int bs = 0; bs < cnt; bs += 64) {
            int idx = bs + lane;
            int s = t;
            float e0 = 0.f, e1 = 0.f;
            if (idx < cnt) {
                s = (idx < deg) ? csrc[beg + idx] : t;
                float2 av = aj2[s];
                float a0 = ait.x + av.x; a0 = a0 < 0.f ? 0.2f * a0 : a0;
                float a1 = ait.y + av.y; a1 = a1 < 0.f ? 0.2f * a1 : a1;
                e0 = expf(a0 - mx0);
                e1 = expf(a1 - mx1);
            }
            den0 += e0;
            den1 += e1;
            int m = min(64, cnt - bs);
            for (int j = 0; j < m; ++j) {
                int sj = __shfl(s, j, 64);
                float w0 = __shfl(e0, j, 64);
                float w1 = __shfl(e1, j, 64);
                unsigned v = xtb[(size_t)sj * DH + lane];
                acc0 += w0 * __uint_as_float(v << 16);
                acc1 += w1 * __uint_as_float(v & 0xffff0000u);
            }
        }
        den0 = wsum(den0);
        den1 = wsum(den1);
        u = 0.5f * (acc0 / (den0 + 1e-16f) + acc1 / (den1 + 1e-16f));
    }
    // ---- HypAct: expmap0 -> proj -> logmap0 -> leaky -> expmap0 -> proj ----
    float Su = wsum(u * u);
    float nu = fmaxf(sqrtf(Su), 1e-15f);
    float e = tanhf(nu) * u / nu;
    float Se = wsum(e * e);
    float ne = fmaxf(sqrtf(Se), 1e-15f);
    if (ne > MAXN_F) e *= MAXN_F / ne;
    float Sh = wsum(e * e);
    float nh = fmaxf(sqrtf(Sh), 1e-15f);
    float g = atanhf(fminf(nh, 1.f - 1e-7f)) / nh;
    float ht = g * e;
    ht = ht < 0.f ? 0.01f * ht : ht;
    float St = wsum(ht * ht);
    float nt = fmaxf(sqrtf(St), 1e-15f);
    float o = tanhf(nt) * ht / nt;
    float So = wsum(o * o);
    float no = fmaxf(sqrtf(So), 1e-15f);
    if (no > MAXN_F) o *= MAXN_F / no;
    out[(size_t)t * DH + lane] = o;
}

extern "C" void kernel_launch(void* const* d_in, const int* in_sizes, int n_in,
                              void* d_out, int out_size, void* d_ws, size_t ws_size,
                              hipStream_t stream) {
    const float* x    = (const float*)d_in[0];
    const int*   eidx = (const int*)d_in[1];
    const float* W    = (const float*)d_in[2];
    const float* bias = (const float*)d_in[3];
    const float* atti = (const float*)d_in[4];
    const float* attj = (const float*)d_in[5];
    float* out = (float*)d_out;

    const int n = in_sizes[0] / DD;  // 100000
    const int E = in_sizes[1] / 2;   // 600000
    const size_t nf = (size_t)n;

    unsigned* xtb = (unsigned*)d_ws;            // n*64 dwords (bf16 pairs)
    float* ai  = (float*)(xtb + nf * DH);       // 2n
    float* aj  = ai + 2 * nf;                   // 2n
    int* deg    = (int*)(aj + 2 * nf);          // n
    int* rowptr = deg + nf;                     // n+1
    int* cursor = rowptr + nf + 1;              // n
    int* bsum   = cursor + nf;                  // 256
    int* csrc   = bsum + 256;                   // E

    const int nb = (n + 1023) / 1024;  // scan chunks (<=256)

    hipMemsetAsync(deg, 0, nf * sizeof(int), stream);
    gemm_node_k<<<NB_GEMM, 256, 0, stream>>>(x, W, bias, atti, attj, eidx, deg,
                                             xtb, ai, aj, n, E);
    scan1_k<<<nb, 256, 0, stream>>>(deg, bsum, n);
    scan23_k<<<nb, 256, 0, stream>>>(deg, bsum, rowptr, cursor, n, E, nb);
    scatter_k<<<(E + 255) / 256, 256, 0, stream>>>(eidx, cursor, csrc, E);
    agg_fused_k<<<(n + 3) / 4, 256, 0, stream>>>(rowptr, csrc, ai, aj, xtb, out, n);
}

// Round 15
// 293.137 us; speedup vs baseline: 1.0869x; 1.0869x over previous
//
#include <hip/hip_runtime.h>
#include <hip/hip_bf16.h>
#include <math.h>

#define DD 128
#define DH 64
#define BM 64
#define MAXN_F (1.0f - 4e-3f)

__device__ inline float wsum(float v) {
#pragma unroll
    for (int off = 32; off > 0; off >>= 1) v += __shfl_xor(v, off, 64);
    return v;
}
__device__ inline float wmax(float v) {
#pragma unroll
    for (int off = 32; off > 0; off >>= 1) v = fmaxf(v, __shfl_xor(v, off, 64));
    return v;
}
__device__ inline int wsumi(int v) {
#pragma unroll
    for (int off = 32; off > 0; off >>= 1) v += __shfl_xor(v, off, 64);
    return v;
}
__device__ inline unsigned short f2bf16(float x) {
    unsigned u = __float_as_uint(x);
    u += 0x7fffu + ((u >> 16) & 1u);   // RNE
    return (unsigned short)(u >> 16);
}
__device__ inline unsigned packbf(float a, float b) {
    return (unsigned)f2bf16(a) | ((unsigned)f2bf16(b) << 16);
}

// ---- fused GEMM (mx = x@W^T) + per-wave bias + analytic epilogue + histogram
// block 256 = 4 waves, BM=64 rows, fp32 x tile (32 KB). acc[8][4] in registers;
// W k-loop register double-buffered (prefetch k4+1 while computing k4).
__global__ __launch_bounds__(256) void gemm_node_k(
    const float* __restrict__ x, const float* __restrict__ W,
    const float* __restrict__ bias,
    const float* __restrict__ atti, const float* __restrict__ attj,
    const int* __restrict__ eidx, int* __restrict__ deg,
    unsigned* __restrict__ xtb, float* __restrict__ ai, float* __restrict__ aj,
    int n, int E) {
    __shared__ float xs[BM * DD];   // 32 KB fp32 x tile
    __shared__ float sred[6][BM];
    __shared__ float sxq[BM];
    __shared__ float sab[BM * 2];
    const int row0 = blockIdx.x * BM;
    const int tid = threadIdx.x;
    const int lane = tid & 63;
    const float4* x4 = reinterpret_cast<const float4*>(x);
    float4* xs4 = reinterpret_cast<float4*>(xs);
    // ---- stage x tile + fused |x|^2 partials ----
    float px[8];
#pragma unroll
    for (int j = 0; j < 8; ++j) {
        int idx = tid + j * 256;  // row = idx>>5, col4 = idx&31
        int r = idx >> 5;
        float4 v = make_float4(0.f, 0.f, 0.f, 0.f);
        if (row0 + r < n) v = x4[(size_t)(row0 + r) * 32 + (idx & 31)];
        xs4[idx] = v;
        px[j] = v.x * v.x + v.y * v.y + v.z * v.z + v.w * v.w;
    }
#pragma unroll
    for (int j = 0; j < 8; ++j) {
#pragma unroll
        for (int off = 16; off > 0; off >>= 1) px[j] += __shfl_xor(px[j], off, 32);
    }
    if ((tid & 31) == 0) {
        int g = tid >> 5;
#pragma unroll
        for (int j = 0; j < 8; ++j) sxq[g + j * 8] = px[j];
    }
    // ---- per-wave bias/att pipeline (registers only) ----
    float b0 = bias[lane], b1 = bias[64 + lane];
    float ai0 = atti[lane], ai1 = atti[64 + lane];
    float aj0 = attj[lane], aj1 = attj[64 + lane];
    float Sb = wsum(b0 * b0 + b1 * b1);
    float nb_ = fmaxf(sqrtf(Sb), 1e-15f);
    float th = tanhf(nb_) / nb_;
    float e0 = th * b0, e1 = th * b1;
    float Se = wsum(e0 * e0 + e1 * e1);
    float ne = fmaxf(sqrtf(Se), 1e-15f);
    if (ne > MAXN_F) { float sc = MAXN_F / ne; e0 *= sc; e1 *= sc; }
    float y2v = wsum(e0 * e0 + e1 * e1);
    float Yi0 = wsum(e0 * ai0), Yi1 = wsum(e1 * ai1);
    float Yj0 = wsum(e0 * aj0), Yj1 = wsum(e1 * aj1);
    const int c4 = tid & 31;
    float hbv[4], aiv[4], ajv[4];
    hbv[0] = __shfl(e0, c4, 64);  hbv[1] = __shfl(e0, 32 + c4, 64);
    hbv[2] = __shfl(e1, c4, 64);  hbv[3] = __shfl(e1, 32 + c4, 64);
    aiv[0] = __shfl(ai0, c4, 64); aiv[1] = __shfl(ai0, 32 + c4, 64);
    aiv[2] = __shfl(ai1, c4, 64); aiv[3] = __shfl(ai1, 32 + c4, 64);
    ajv[0] = __shfl(aj0, c4, 64); ajv[1] = __shfl(aj0, 32 + c4, 64);
    ajv[2] = __shfl(aj1, c4, 64); ajv[3] = __shfl(aj1, 32 + c4, 64);
    __syncthreads();
    // ---- GEMM with W register double-buffer ----
    const int rg = tid >> 5;  // row group 0..7
    float acc[8][4];
#pragma unroll
    for (int rr = 0; rr < 8; ++rr)
#pragma unroll
        for (int cc = 0; cc < 4; ++cc) acc[rr][cc] = 0.f;
    const float4* W4 = reinterpret_cast<const float4*>(W);
    const float4* Wc0 = W4 + (c4 + 0) * 32;
    const float4* Wc1 = W4 + (c4 + 32) * 32;
    const float4* Wc2 = W4 + (c4 + 64) * 32;
    const float4* Wc3 = W4 + (c4 + 96) * 32;
    float4 w0c = Wc0[0], w1c = Wc1[0], w2c = Wc2[0], w3c = Wc3[0];
#pragma unroll 4
    for (int k4 = 0; k4 < 32; ++k4) {
        int kn = (k4 + 1) & 31;
        float4 w0n = Wc0[kn];
        float4 w1n = Wc1[kn];
        float4 w2n = Wc2[kn];
        float4 w3n = Wc3[kn];
#pragma unroll
        for (int rr = 0; rr < 8; ++rr) {
            float4 xv = xs4[(rg * 8 + rr) * 32 + k4];
            acc[rr][0] += xv.x * w0c.x + xv.y * w0c.y + xv.z * w0c.z + xv.w * w0c.w;
            acc[rr][1] += xv.x * w1c.x + xv.y * w1c.y + xv.z * w1c.z + xv.w * w1c.w;
            acc[rr][2] += xv.x * w2c.x + xv.y * w2c.y + xv.z * w2c.z + xv.w * w2c.w;
            acc[rr][3] += xv.x * w3c.x + xv.y * w3c.y + xv.z * w3c.z + xv.w * w3c.w;
        }
        w0c = w0n; w1c = w1n; w2c = w2n; w3c = w3n;
    }
    // ---- register reductions: 6 per-row scalars via 32-lane shfl ----
#pragma unroll
    for (int rr = 0; rr < 8; ++rr) {
        float m0 = acc[rr][0], m1 = acc[rr][1], m2 = acc[rr][2], m3 = acc[rr][3];
        float sm = m0 * m0 + m1 * m1 + m2 * m2 + m3 * m3;
        float my = m0 * hbv[0] + m1 * hbv[1] + m2 * hbv[2] + m3 * hbv[3];
        float d0 = m0 * aiv[0] + m1 * aiv[1];
        float d1 = m2 * aiv[2] + m3 * aiv[3];
        float f0 = m0 * ajv[0] + m1 * ajv[1];
        float f1 = m2 * ajv[2] + m3 * ajv[3];
#pragma unroll
        for (int off = 16; off > 0; off >>= 1) {
            sm += __shfl_xor(sm, off, 32);
            my += __shfl_xor(my, off, 32);
            d0 += __shfl_xor(d0, off, 32);
            d1 += __shfl_xor(d1, off, 32);
            f0 += __shfl_xor(f0, off, 32);
            f1 += __shfl_xor(f1, off, 32);
        }
        if (c4 == 0) {
            int row = rg * 8 + rr;
            sred[0][row] = sm; sred[1][row] = my;
            sred[2][row] = d0; sred[3][row] = d1;
            sred[4][row] = f0; sred[5][row] = f1;
        }
    }
    __syncthreads();
    // ---- per-row scalar chain (64 threads; Y*/y2v live in wave-0 registers) --
    if (tid < BM) {
        int grow = row0 + tid;
        float Sx  = sxq[tid];
        float Sm  = sred[0][tid];
        float My  = sred[1][tid];
        float Di0 = sred[2][tid];
        float Di1 = sred[3][tid];
        float Dj0 = sred[4][tid];
        float Dj1 = sred[5][tid];
        float xn = fmaxf(sqrtf(Sx), 1e-15f);
        float mxn = fmaxf(sqrtf(Sm), 1e-15f);
        float art = atanhf(fminf(xn, 1.f - 1e-7f));
        float tn = tanhf(mxn / xn * art);
        float rho = (Sm == 0.f) ? 0.f : tn / mxn;
        float pn = (Sm == 0.f) ? 0.f : tn;
        if (pn > MAXN_F) { rho *= MAXN_F / pn; pn = MAXN_F; }
        float X2 = pn * pn, XY = rho * My;
        float ca = 1.f + 2.f * XY + y2v;
        float cb = 1.f - X2;
        float dn = fmaxf(1.f + 2.f * XY + X2 * y2v, 1e-15f);
        float Sh = (ca * ca * X2 + 2.f * ca * cb * XY + cb * cb * y2v) / (dn * dn);
        float nraw = fmaxf(sqrtf(Sh), 1e-15f);
        float scp = 1.f, nh = nraw;
        if (nraw > MAXN_F) { scp = MAXN_F / nraw; nh = MAXN_F; }
        float g = atanhf(fminf(nh, 1.f - 1e-7f)) / nh;
        float gs = g * scp / dn;
        float al = gs * ca * rho;
        float be = gs * cb;
        sab[tid * 2] = al;
        sab[tid * 2 + 1] = be;
        if (grow < n) {
            reinterpret_cast<float2*>(ai)[grow] =
                make_float2(al * Di0 + be * Yi0, al * Di1 + be * Yi1);
            reinterpret_cast<float2*>(aj)[grow] =
                make_float2(al * Dj0 + be * Yj0, al * Dj1 + be * Yj1);
        }
    }
    __syncthreads();
    // ---- xtb = bf16 pack of alpha*acc + beta*hb (interleaved heads) ----
#pragma unroll
    for (int rr = 0; rr < 8; ++rr) {
        int row = rg * 8 + rr;
        int grow = row0 + row;
        if (grow < n) {
            float al = sab[row * 2], be = sab[row * 2 + 1];
            float t0 = al * acc[rr][0] + be * hbv[0];  // head0 dim c4
            float t1 = al * acc[rr][1] + be * hbv[1];  // head0 dim 32+c4
            float t2 = al * acc[rr][2] + be * hbv[2];  // head1 dim c4
            float t3 = al * acc[rr][3] + be * hbv[3];  // head1 dim 32+c4
            xtb[(size_t)grow * DH + c4]      = packbf(t0, t2);
            xtb[(size_t)grow * DH + 32 + c4] = packbf(t1, t3);
        }
    }
    // ---- edge histogram tail ----
    {
        int perB = (E + gridDim.x - 1) / gridDim.x;
        int eb = blockIdx.x * perB;
        int ee = min(E, eb + perB);
        for (int e = eb + tid; e < ee; e += 256) atomicAdd(&deg[eidx[e]], 1);
    }
}

// ---------------- scan1: per-1024-chunk sums ----------------
__global__ __launch_bounds__(256) void scan1_k(const int* __restrict__ deg,
                                               int* __restrict__ bsum, int n) {
    int b = blockIdx.x, tid = threadIdx.x;
    int i0 = b * 1024 + tid * 4;
    int s = 0;
#pragma unroll
    for (int k = 0; k < 4; ++k)
        if (i0 + k < n) s += deg[i0 + k];
    s = wsumi(s);
    __shared__ int sm[4];
    if ((tid & 63) == 0) sm[tid >> 6] = s;
    __syncthreads();
    if (tid == 0) bsum[b] = sm[0] + sm[1] + sm[2] + sm[3];
}

// ---------------- scan23: top-level scan + rowptr/cursor ----------------
__global__ __launch_bounds__(256) void scan23_k(const int* __restrict__ deg,
                                                const int* __restrict__ bsum,
                                                int* __restrict__ rowptr,
                                                int* __restrict__ cursor,
                                                int n, int E, int nb) {
    int b = blockIdx.x, tid = threadIdx.x;
    __shared__ int sm2[256];
    int v = (tid < nb) ? bsum[tid] : 0;
    sm2[tid] = v;
    __syncthreads();
    for (int off = 1; off < 256; off <<= 1) {
        int u = (tid >= off) ? sm2[tid - off] : 0;
        __syncthreads();
        sm2[tid] += u;
        __syncthreads();
    }
    __shared__ int myoff;
    if (tid == 0) myoff = sm2[b] - bsum[b];
    __syncthreads();
    int i0 = b * 1024 + tid * 4;
    int d[4];
#pragma unroll
    for (int k = 0; k < 4; ++k) d[k] = (i0 + k < n) ? deg[i0 + k] : 0;
    int ts = d[0] + d[1] + d[2] + d[3];
    __shared__ int sm[256];
    sm[tid] = ts;
    __syncthreads();
    for (int off = 1; off < 256; off <<= 1) {
        int u = (tid >= off) ? sm[tid - off] : 0;
        __syncthreads();
        sm[tid] += u;
        __syncthreads();
    }
    int base = myoff + sm[tid] - ts;
    int pre = 0;
#pragma unroll
    for (int k = 0; k < 4; ++k) {
        if (i0 + k < n) {
            rowptr[i0 + k] = base + pre;
            cursor[i0 + k] = base + pre;
        }
        pre += d[k];
    }
    if (b == 0 && tid == 0) rowptr[n] = E;
}

// ---------------- CSR scatter ----------------
__global__ __launch_bounds__(256) void scatter_k(const int* __restrict__ eidx,
                                                 int* __restrict__ cursor,
                                                 int* __restrict__ csrc, int E) {
    int e = blockIdx.x * 256 + threadIdx.x;
    if (e >= E) return;
    int t = eidx[e], s = eidx[E + e];
    int pos = atomicAdd(&cursor[t], 1);
    csrc[pos] = s;
}

// ---------------- fused softmax + aggregation + HypAct ----------------
__global__ __launch_bounds__(256) void agg_fused_k(
    const int* __restrict__ rowptr, const int* __restrict__ csrc,
    const float* __restrict__ ai, const float* __restrict__ aj,
    const unsigned* __restrict__ xtb, float* __restrict__ out, int n) {
    int t = (blockIdx.x * 256 + threadIdx.x) >> 6;
    int lane = threadIdx.x & 63;
    if (t >= n) return;
    const int beg = rowptr[t];
    const int deg = rowptr[t + 1] - beg;
    const int cnt = deg + 1;  // + self loop
    float2 ait = reinterpret_cast<const float2*>(ai)[t];
    const float2* aj2 = reinterpret_cast<const float2*>(aj);
    float u;
    if (cnt <= 64) {
        // ---- single-pass fast path ----
        int s_ = t;
        if (lane < deg) s_ = csrc[beg + lane];
        float a0 = -1e30f, a1 = -1e30f;
        if (lane < cnt) {
            float2 av = aj2[s_];
            a0 = ait.x + av.x; a0 = a0 < 0.f ? 0.2f * a0 : a0;
            a1 = ait.y + av.y; a1 = a1 < 0.f ? 0.2f * a1 : a1;
        }
        float mx0 = wmax(a0), mx1 = wmax(a1);
        float e0 = (lane < cnt) ? expf(a0 - mx0) : 0.f;
        float e1 = (lane < cnt) ? expf(a1 - mx1) : 0.f;
        float den0 = wsum(e0), den1 = wsum(e1);
        float w0s = 0.5f * e0 / (den0 + 1e-16f);
        float w1s = 0.5f * e1 / (den1 + 1e-16f);
        float acc = 0.f;
        for (int j = 0; j < cnt; ++j) {
            int sj = __shfl(s_, j, 64);
            float w0 = __shfl(w0s, j, 64);
            float w1 = __shfl(w1s, j, 64);
            unsigned v = xtb[(size_t)sj * DH + lane];
            acc += w0 * __uint_as_float(v << 16) +
                   w1 * __uint_as_float(v & 0xffff0000u);
        }
        u = acc;
    } else {
        // ---- general two-pass path (rare: deg > 63) ----
        float mx0 = -1e30f, mx1 = -1e30f;
        for (int bs = 0; bs < cnt; bs += 64) {
            int idx = bs + lane;
            float a0 = -1e30f, a1 = -1e30f;
            if (idx < cnt) {
                int s = (idx < deg) ? csrc[beg + idx] : t;
                float2 av = aj2[s];
                a0 = ait.x + av.x; a0 = a0 < 0.f ? 0.2f * a0 : a0;
                a1 = ait.y + av.y; a1 = a1 < 0.f ? 0.2f * a1 : a1;
            }
            mx0 = fmaxf(mx0, a0);
            mx1 = fmaxf(mx1, a1);
        }
        mx0 = wmax(mx0);
        mx1 = wmax(mx1);
        float acc0 = 0.f, acc1 = 0.f, den0 = 0.f, den1 = 0.f;
        for (int bs = 0; bs < cnt; bs += 64) {
            int idx = bs + lane;
            int s = t;
            float e0 = 0.f, e1 = 0.f;
            if (idx < cnt) {
                s = (idx < deg) ? csrc[beg + idx] : t;
                float2 av = aj2[s];
                float a0 = ait.x + av.x; a0 = a0 < 0.f ? 0.2f * a0 : a0;
                float a1 = ait.y + av.y; a1 = a1 < 0.f ? 0.2f * a1 : a1;
                e0 = expf(a0 - mx0);
                e1 = expf(a1 - mx1);
            }
            den0 += e0;
            den1 += e1;
            int m = min(64, cnt - bs);
            for (int j = 0; j < m; ++j) {
                int sj = __shfl(s, j, 64);
                float w0 = __shfl(e0, j, 64);
                float w1 = __shfl(e1, j, 64);
                unsigned v = xtb[(size_t)sj * DH + lane];
                acc0 += w0 * __uint_as_float(v << 16);
                acc1 += w1 * __uint_as_float(v & 0xffff0000u);
            }
        }
        den0 = wsum(den0);
        den1 = wsum(den1);
        u = 0.5f * (acc0 / (den0 + 1e-16f) + acc1 / (den1 + 1e-16f));
    }
    // ---- HypAct: expmap0 -> proj -> logmap0 -> leaky -> expmap0 -> proj ----
    float Su = wsum(u * u);
    float nu = fmaxf(sqrtf(Su), 1e-15f);
    float e = tanhf(nu) * u / nu;
    float Se = wsum(e * e);
    float ne = fmaxf(sqrtf(Se), 1e-15f);
    if (ne > MAXN_F) e *= MAXN_F / ne;
    float Sh = wsum(e * e);
    float nh = fmaxf(sqrtf(Sh), 1e-15f);
    float g = atanhf(fminf(nh, 1.f - 1e-7f)) / nh;
    float ht = g * e;
    ht = ht < 0.f ? 0.01f * ht : ht;
    float St = wsum(ht * ht);
    float nt = fmaxf(sqrtf(St), 1e-15f);
    float o = tanhf(nt) * ht / nt;
    float So = wsum(o * o);
    float no = fmaxf(sqrtf(So), 1e-15f);
    if (no > MAXN_F) o *= MAXN_F / no;
    out[(size_t)t * DH + lane] = o;
}

extern "C" void kernel_launch(void* const* d_in, const int* in_sizes, int n_in,
                              void* d_out, int out_size, void* d_ws, size_t ws_size,
                              hipStream_t stream) {
    const float* x    = (const float*)d_in[0];
    const int*   eidx = (const int*)d_in[1];
    const float* W    = (const float*)d_in[2];
    const float* bias = (const float*)d_in[3];
    const float* atti = (const float*)d_in[4];
    const float* attj = (const float*)d_in[5];
    float* out = (float*)d_out;

    const int n = in_sizes[0] / DD;  // 100000
    const int E = in_sizes[1] / 2;   // 600000
    const size_t nf = (size_t)n;

    unsigned* xtb = (unsigned*)d_ws;            // n*64 dwords (bf16 pairs)
    float* ai  = (float*)(xtb + nf * DH);       // 2n
    float* aj  = ai + 2 * nf;                   // 2n
    int* deg    = (int*)(aj + 2 * nf);          // n
    int* rowptr = deg + nf;                     // n+1
    int* cursor = rowptr + nf + 1;              // n
    int* bsum   = cursor + nf;                  // 256
    int* csrc   = bsum + 256;                   // E

    const int nb = (n + 1023) / 1024;  // scan chunks (<=256)
    const int ngemm = (n + BM - 1) / BM;

    hipMemsetAsync(deg, 0, nf * sizeof(int), stream);
    gemm_node_k<<<ngemm, 256, 0, stream>>>(x, W, bias, atti, attj, eidx, deg,
                                           xtb, ai, aj, n, E);
    scan1_k<<<nb, 256, 0, stream>>>(deg, bsum, n);
    scan23_k<<<nb, 256, 0, stream>>>(deg, bsum, rowptr, cursor, n, E, nb);
    scatter_k<<<(E + 255) / 256, 256, 0, stream>>>(eidx, cursor, csrc, E);
    agg_fused_k<<<(n + 3) / 4, 256, 0, stream>>>(rowptr, csrc, ai, aj, xtb, out, n);
}

// Round 16
// 287.644 us; speedup vs baseline: 1.1076x; 1.0191x over previous
//
#include <hip/hip_runtime.h>
#include <hip/hip_bf16.h>
#include <math.h>

#define DD 128
#define DH 64
#define MAXN_F (1.0f - 4e-3f)
#define NTHR 512
#define NBLK 512   // 2 blocks/CU, whole grid resident

__device__ inline float wsum(float v) {
#pragma unroll
    for (int off = 32; off > 0; off >>= 1) v += __shfl_xor(v, off, 64);
    return v;
}
__device__ inline float wmax(float v) {
#pragma unroll
    for (int off = 32; off > 0; off >>= 1) v = fmaxf(v, __shfl_xor(v, off, 64));
    return v;
}
__device__ inline int wsumi(int v) {
#pragma unroll
    for (int off = 32; off > 0; off >>= 1) v += __shfl_xor(v, off, 64);
    return v;
}
__device__ inline unsigned short f2bf16(float x) {
    unsigned u = __float_as_uint(x);
    u += 0x7fffu + ((u >> 16) & 1u);   // RNE
    return (unsigned short)(u >> 16);
}
__device__ inline unsigned packbf(float a, float b) {
    return (unsigned)f2bf16(a) | ((unsigned)f2bf16(b) << 16);
}
// fast hyperbolics on HW exp2/log2 (args >= 0 here)
__device__ inline float fatanh(float z) {
    return 0.5f * __logf(__fdividef(1.f + z, 1.f - z));
}
__device__ inline float ftanh(float y) {
    y = fminf(y, 10.f);
    float e = __expf(2.f * y);
    return __fdividef(e - 1.f, e + 1.f);
}

// ---- W-in-LDS (fp32) wave-per-row fused kernel -------------------------
// 512 thr = 8 waves, 2 blocks/CU. W staged once (67.6 KB, stride-33 float4).
// Each wave grid-strides rows: x row -> wave-private LDS slot (512 B), k-loop
// reads x uniform (broadcast) + 2 W float4/iter, 8 FMA. No barriers in loop.
__global__ __launch_bounds__(NTHR) void gemm_node_k(
    const float* __restrict__ x, const float* __restrict__ W,
    const float* __restrict__ bias,
    const float* __restrict__ atti, const float* __restrict__ attj,
    const int* __restrict__ eidx, int* __restrict__ deg,
    unsigned* __restrict__ xtb, float* __restrict__ ai, float* __restrict__ aj,
    int n, int E) {
    __shared__ float wlds[128 * 132];      // 67.6 KB: col*132 + k4*4 (+pad)
    __shared__ float xslot[8][DD];         // 4 KB: per-wave x row
    const int tid = threadIdx.x;
    const int wv = tid >> 6;
    const int lane = tid & 63;
    const float4* W4g = reinterpret_cast<const float4*>(W);
    float4* wlds4 = reinterpret_cast<float4*>(wlds);
    // ---- stage W (fp32, swizzled stride 33 float4 per col) ----
#pragma unroll
    for (int i = 0; i < 8; ++i) {
        int s = tid + i * NTHR;            // 0..4095
        int c = s >> 5, k4 = s & 31;
        wlds4[c * 33 + k4] = W4g[s];
    }
    // ---- per-wave bias/att pipeline (registers only) ----
    float b0 = bias[lane], b1 = bias[64 + lane];
    float ai0 = atti[lane], ai1 = atti[64 + lane];
    float aj0 = attj[lane], aj1 = attj[64 + lane];
    float Sb = wsum(b0 * b0 + b1 * b1);
    float nb_ = fmaxf(sqrtf(Sb), 1e-15f);
    float th = tanhf(nb_) / nb_;
    float e0 = th * b0, e1 = th * b1;
    float Se = wsum(e0 * e0 + e1 * e1);
    float ne = fmaxf(sqrtf(Se), 1e-15f);
    if (ne > MAXN_F) { float sc = MAXN_F / ne; e0 *= sc; e1 *= sc; }
    float y2v = wsum(e0 * e0 + e1 * e1);
    float Yi0 = wsum(e0 * ai0), Yi1 = wsum(e1 * ai1);
    float Yj0 = wsum(e0 * aj0), Yj1 = wsum(e1 * aj1);
    __syncthreads();  // W staged
    // ---- row loop: one wave per row ----
    const int gw = blockIdx.x * 8 + wv;
    const int nw = NBLK * 8;
    const float2* x2 = reinterpret_cast<const float2*>(x);
    const float4* w0p = wlds4 + (size_t)lane * 33;        // col = lane
    const float4* w1p = wlds4 + (size_t)(lane + 64) * 33; // col = 64+lane
    float* slot = xslot[wv];
    int r = gw;
    float c0 = 0.f, c1 = 0.f;
    if (r < n) { float2 v = x2[(size_t)r * 64 + lane]; c0 = v.x; c1 = v.y; }
    for (; r < n; r += nw) {
        slot[2 * lane] = c0;
        slot[2 * lane + 1] = c1;
        float Sx = wsum(c0 * c0 + c1 * c1);
        int rn = r + nw;
        float n0 = 0.f, n1 = 0.f;
        if (rn < n) { float2 v = x2[(size_t)rn * 64 + lane]; n0 = v.x; n1 = v.y; }
        __threadfence_block();  // order slot writes before uniform reads
        const float4* sp = reinterpret_cast<const float4*>(slot);
        float m0 = 0.f, m1 = 0.f;
#pragma unroll
        for (int p = 0; p < 32; ++p) {
            float4 xv = sp[p];        // uniform address -> broadcast
            float4 w0 = w0p[p];
            float4 w1 = w1p[p];
            m0 += xv.x * w0.x + xv.y * w0.y + xv.z * w0.z + xv.w * w0.w;
            m1 += xv.x * w1.x + xv.y * w1.y + xv.z * w1.z + xv.w * w1.w;
        }
        // 6 per-row scalars via 64-lane reductions
        float Sm  = wsum(m0 * m0 + m1 * m1);
        float My  = wsum(m0 * e0 + m1 * e1);
        float Di0 = wsum(m0 * ai0), Di1 = wsum(m1 * ai1);
        float Dj0 = wsum(m0 * aj0), Dj1 = wsum(m1 * aj1);
        // analytic scalar chain (redundant on all lanes)
        float xn = fmaxf(sqrtf(Sx), 1e-15f);
        float mxn = fmaxf(sqrtf(Sm), 1e-15f);
        float art = fatanh(fminf(xn, 1.f - 1e-7f));
        float tn = ftanh(__fdividef(mxn, xn) * art);
        float rho = (Sm == 0.f) ? 0.f : __fdividef(tn, mxn);
        float pn = (Sm == 0.f) ? 0.f : tn;
        if (pn > MAXN_F) { rho *= MAXN_F / pn; pn = MAXN_F; }
        float X2 = pn * pn, XY = rho * My;
        float ca = 1.f + 2.f * XY + y2v;
        float cb = 1.f - X2;
        float dn = fmaxf(1.f + 2.f * XY + X2 * y2v, 1e-15f);
        float Sh = __fdividef(ca * ca * X2 + 2.f * ca * cb * XY + cb * cb * y2v,
                              dn * dn);
        float nraw = fmaxf(sqrtf(Sh), 1e-15f);
        float scp = 1.f, nh = nraw;
        if (nraw > MAXN_F) { scp = MAXN_F / nraw; nh = MAXN_F; }
        float g = __fdividef(fatanh(fminf(nh, 1.f - 1e-7f)), nh);
        float gs = __fdividef(g * scp, dn);
        float al = gs * ca * rho;
        float be = gs * cb;
        xtb[(size_t)r * DH + lane] = packbf(al * m0 + be * e0, al * m1 + be * e1);
        if (lane == 0) {
            reinterpret_cast<float2*>(ai)[r] =
                make_float2(al * Di0 + be * Yi0, al * Di1 + be * Yi1);
            reinterpret_cast<float2*>(aj)[r] =
                make_float2(al * Dj0 + be * Yj0, al * Dj1 + be * Yj1);
        }
        c0 = n0; c1 = n1;
    }
    // ---- edge histogram tail ----
    {
        int perB = (E + NBLK - 1) / NBLK;
        int eb = blockIdx.x * perB;
        int ee = min(E, eb + perB);
        for (int e = eb + tid; e < ee; e += NTHR) atomicAdd(&deg[eidx[e]], 1);
    }
}

// ---------------- scan1: per-1024-chunk sums ----------------
__global__ __launch_bounds__(256) void scan1_k(const int* __restrict__ deg,
                                               int* __restrict__ bsum, int n) {
    int b = blockIdx.x, tid = threadIdx.x;
    int i0 = b * 1024 + tid * 4;
    int s = 0;
#pragma unroll
    for (int k = 0; k < 4; ++k)
        if (i0 + k < n) s += deg[i0 + k];
    s = wsumi(s);
    __shared__ int sm[4];
    if ((tid & 63) == 0) sm[tid >> 6] = s;
    __syncthreads();
    if (tid == 0) bsum[b] = sm[0] + sm[1] + sm[2] + sm[3];
}

// ---------------- scan23: top-level scan + rowptr/cursor ----------------
__global__ __launch_bounds__(256) void scan23_k(const int* __restrict__ deg,
                                                const int* __restrict__ bsum,
                                                int* __restrict__ rowptr,
                                                int* __restrict__ cursor,
                                                int n, int E, int nb) {
    int b = blockIdx.x, tid = threadIdx.x;
    __shared__ int sm2[256];
    int v = (tid < nb) ? bsum[tid] : 0;
    sm2[tid] = v;
    __syncthreads();
    for (int off = 1; off < 256; off <<= 1) {
        int u = (tid >= off) ? sm2[tid - off] : 0;
        __syncthreads();
        sm2[tid] += u;
        __syncthreads();
    }
    __shared__ int myoff;
    if (tid == 0) myoff = sm2[b] - bsum[b];
    __syncthreads();
    int i0 = b * 1024 + tid * 4;
    int d[4];
#pragma unroll
    for (int k = 0; k < 4; ++k) d[k] = (i0 + k < n) ? deg[i0 + k] : 0;
    int ts = d[0] + d[1] + d[2] + d[3];
    __shared__ int sm[256];
    sm[tid] = ts;
    __syncthreads();
    for (int off = 1; off < 256; off <<= 1) {
        int u = (tid >= off) ? sm[tid - off] : 0;
        __syncthreads();
        sm[tid] += u;
        __syncthreads();
    }
    int base = myoff + sm[tid] - ts;
    int pre = 0;
#pragma unroll
    for (int k = 0; k < 4; ++k) {
        if (i0 + k < n) {
            rowptr[i0 + k] = base + pre;
            cursor[i0 + k] = base + pre;
        }
        pre += d[k];
    }
    if (b == 0 && tid == 0) rowptr[n] = E;
}

// ---------------- CSR scatter ----------------
__global__ __launch_bounds__(256) void scatter_k(const int* __restrict__ eidx,
                                                 int* __restrict__ cursor,
                                                 int* __restrict__ csrc, int E) {
    int e = blockIdx.x * 256 + threadIdx.x;
    if (e >= E) return;
    int t = eidx[e], s = eidx[E + e];
    int pos = atomicAdd(&cursor[t], 1);
    csrc[pos] = s;
}

// ---------------- fused softmax + aggregation + HypAct ----------------
__global__ __launch_bounds__(256) void agg_fused_k(
    const int* __restrict__ rowptr, const int* __restrict__ csrc,
    const float* __restrict__ ai, const float* __restrict__ aj,
    const unsigned* __restrict__ xtb, float* __restrict__ out, int n) {
    int t = (blockIdx.x * 256 + threadIdx.x) >> 6;
    int lane = threadIdx.x & 63;
    if (t >= n) return;
    const int beg = rowptr[t];
    const int deg = rowptr[t + 1] - beg;
    const int cnt = deg + 1;  // + self loop
    float2 ait = reinterpret_cast<const float2*>(ai)[t];
    const float2* aj2 = reinterpret_cast<const float2*>(aj);
    float u;
    if (cnt <= 64) {
        // ---- single-pass fast path ----
        int s_ = t;
        if (lane < deg) s_ = csrc[beg + lane];
        float a0 = -1e30f, a1 = -1e30f;
        if (lane < cnt) {
            float2 av = aj2[s_];
            a0 = ait.x + av.x; a0 = a0 < 0.f ? 0.2f * a0 : a0;
            a1 = ait.y + av.y; a1 = a1 < 0.f ? 0.2f * a1 : a1;
        }
        float mx0 = wmax(a0), mx1 = wmax(a1);
        float e0 = (lane < cnt) ? expf(a0 - mx0) : 0.f;
        float e1 = (lane < cnt) ? expf(a1 - mx1) : 0.f;
        float den0 = wsum(e0), den1 = wsum(e1);
        float w0s = 0.5f * e0 / (den0 + 1e-16f);
        float w1s = 0.5f * e1 / (den1 + 1e-16f);
        float acc = 0.f;
        for (int j = 0; j < cnt; ++j) {
            int sj = __shfl(s_, j, 64);
            float w0 = __shfl(w0s, j, 64);
            float w1 = __shfl(w1s, j, 64);
            unsigned v = xtb[(size_t)sj * DH + lane];
            acc += w0 * __uint_as_float(v << 16) +
                   w1 * __uint_as_float(v & 0xffff0000u);
        }
        u = acc;
    } else {
        // ---- general two-pass path (rare: deg > 63) ----
        float mx0 = -1e30f, mx1 = -1e30f;
        for (int bs = 0; bs < cnt; bs += 64) {
            int idx = bs + lane;
            float a0 = -1e30f, a1 = -1e30f;
            if (idx < cnt) {
                int s = (idx < deg) ? csrc[beg + idx] : t;
                float2 av = aj2[s];
                a0 = ait.x + av.x; a0 = a0 < 0.f ? 0.2f * a0 : a0;
                a1 = ait.y + av.y; a1 = a1 < 0.f ? 0.2f * a1 : a1;
            }
            mx0 = fmaxf(mx0, a0);
            mx1 = fmaxf(mx1, a1);
        }
        mx0 = wmax(mx0);
        mx1 = wmax(mx1);
        float acc0 = 0.f, acc1 = 0.f, den0 = 0.f, den1 = 0.f;
        for (int bs = 0; bs < cnt; bs += 64) {
            int idx = bs + lane;
            int s = t;
            float e0 = 0.f, e1 = 0.f;
            if (idx < cnt) {
                s = (idx < deg) ? csrc[beg + idx] : t;
                float2 av = aj2[s];
                float a0 = ait.x + av.x; a0 = a0 < 0.f ? 0.2f * a0 : a0;
                float a1 = ait.y + av.y; a1 = a1 < 0.f ? 0.2f * a1 : a1;
                e0 = expf(a0 - mx0);
                e1 = expf(a1 - mx1);
            }
            den0 += e0;
            den1 += e1;
            int m = min(64, cnt - bs);
            for (int j = 0; j < m; ++j) {
                int sj = __shfl(s, j, 64);
                float w0 = __shfl(e0, j, 64);
                float w1 = __shfl(e1, j, 64);
                unsigned v = xtb[(size_t)sj * DH + lane];
                acc0 += w0 * __uint_as_float(v << 16);
                acc1 += w1 * __uint_as_float(v & 0xffff0000u);
            }
        }
        den0 = wsum(den0);
        den1 = wsum(den1);
        u = 0.5f * (acc0 / (den0 + 1e-16f) + acc1 / (den1 + 1e-16f));
    }
    // ---- HypAct: expmap0 -> proj -> logmap0 -> leaky -> expmap0 -> proj ----
    float Su = wsum(u * u);
    float nu = fmaxf(sqrtf(Su), 1e-15f);
    float e = tanhf(nu) * u / nu;
    float Se = wsum(e * e);
    float ne = fmaxf(sqrtf(Se), 1e-15f);
    if (ne > MAXN_F) e *= MAXN_F / ne;
    float Sh = wsum(e * e);
    float nh = fmaxf(sqrtf(Sh), 1e-15f);
    float g = atanhf(fminf(nh, 1.f - 1e-7f)) / nh;
    float ht = g * e;
    ht = ht < 0.f ? 0.01f * ht : ht;
    float St = wsum(ht * ht);
    float nt = fmaxf(sqrtf(St), 1e-15f);
    float o = tanhf(nt) * ht / nt;
    float So = wsum(o * o);
    float no = fmaxf(sqrtf(So), 1e-15f);
    if (no > MAXN_F) o *= MAXN_F / no;
    out[(size_t)t * DH + lane] = o;
}

extern "C" void kernel_launch(void* const* d_in, const int* in_sizes, int n_in,
                              void* d_out, int out_size, void* d_ws, size_t ws_size,
                              hipStream_t stream) {
    const float* x    = (const float*)d_in[0];
    const int*   eidx = (const int*)d_in[1];
    const float* W    = (const float*)d_in[2];
    const float* bias = (const float*)d_in[3];
    const float* atti = (const float*)d_in[4];
    const float* attj = (const float*)d_in[5];
    float* out = (float*)d_out;

    const int n = in_sizes[0] / DD;  // 100000
    const int E = in_sizes[1] / 2;   // 600000
    const size_t nf = (size_t)n;

    unsigned* xtb = (unsigned*)d_ws;            // n*64 dwords (bf16 pairs)
    float* ai  = (float*)(xtb + nf * DH);       // 2n
    float* aj  = ai + 2 * nf;                   // 2n
    int* deg    = (int*)(aj + 2 * nf);          // n
    int* rowptr = deg + nf;                     // n+1
    int* cursor = rowptr + nf + 1;              // n
    int* bsum   = cursor + nf;                  // 256
    int* csrc   = bsum + 256;                   // E

    const int nb = (n + 1023) / 1024;  // scan chunks (<=256)

    hipMemsetAsync(deg, 0, nf * sizeof(int), stream);
    gemm_node_k<<<NBLK, NTHR, 0, stream>>>(x, W, bias, atti, attj, eidx, deg,
                                           xtb, ai, aj, n, E);
    scan1_k<<<nb, 256, 0, stream>>>(deg, bsum, n);
    scan23_k<<<nb, 256, 0, stream>>>(deg, bsum, rowptr, cursor, n, E, nb);
    scatter_k<<<(E + 255) / 256, 256, 0, stream>>>(eidx, cursor, csrc, E);
    agg_fused_k<<<(n + 3) / 4, 256, 0, stream>>>(rowptr, csrc, ai, aj, xtb, out, n);
}